// Round 9
// baseline (357.596 us; speedup 1.0000x reference)
//
#include <hip/hip_runtime.h>
#include <hip/hip_cooperative_groups.h>

namespace cg = cooperative_groups;

// Bahdanau additive attention, fp32.
// score[b,q,v] = S - 2*sum_u s_u / (1 + Eq[q,u]*Ek[v,u]),  E* = exp(2*proj)
// Primary: single cooperative kernel (grid=512, 2 blocks/CU guaranteed).
// Fallback (if coop launch rejected): verified round-8 3-kernel path.

#define TQ 256
#define TV 1024
#define BB 4
#define DD 128
#define UU 128
#define NEG_INF -1e9f
#define C2LOG2E 2.8853900817779268f   // 2*log2(e)
#define GRID_BLKS 512                 // 2 blocks/CU — co-residency safe

// 4-batched reciprocal: 17 VALU + 1 rcp per 4 score terms
#define QUAD(Av, Kv, acc)                                          \
  { float d0 = __builtin_fmaf(Av.x, Kv.x, 1.f);                    \
    float d1 = __builtin_fmaf(Av.y, Kv.y, 1.f);                    \
    float d2 = __builtin_fmaf(Av.z, Kv.z, 1.f);                    \
    float d3 = __builtin_fmaf(Av.w, Kv.w, 1.f);                    \
    float m01 = d0 * d1, m23 = d2 * d3;                            \
    float R = __builtin_amdgcn_rcpf(m01 * m23);                    \
    float q01 = R * m23, q23 = R * m01;                            \
    acc = __builtin_fmaf(sv.x, q01 * d1, acc);                     \
    acc = __builtin_fmaf(sv.y, q01 * d0, acc);                     \
    acc = __builtin_fmaf(sv.z, q23 * d3, acc);                     \
    acc = __builtin_fmaf(sv.w, q23 * d2, acc); }

struct Params {
  const float* query; const float* value; const int* mask;
  const float* W1; const float* W2; const float* scale;
  float* out; float* Eq; float* Ek; float* scores;
  int* vidx; int* nvalid; float* Ssum;
};

union SharedU {
  struct { float4 eq[16 * 32]; float4 ek[64 * 32]; } sc;             // 40960 B
  struct { float p[4][TV]; float part[3][4][DD]; float red[4]; } cx; // 22544 B
  struct { float Wl[DD * UU]; float xs[8][DD]; } pj;                 // 69632 B? no:
  // NOTE: pj would be 68 KB > sc; proj below is LDS-free (registers + L2).
  struct { int wsum[4]; float sred[2]; } cp;
};

__global__ __launch_bounds__(256, 2) void fused_kernel(Params P) {
  __shared__ SharedU u;
  cg::grid_group grid = cg::this_grid();
  const int bid  = blockIdx.x;
  const int t    = threadIdx.x;
  const int lane = t & 63;
  const int wid  = t >> 6;

  // ===== P0/P1: units 0..3 = compact(b), units 4..643 = proj 8 rows =======
  for (int unit = bid; unit < BB + (TQ + TV) * BB / 8; unit += GRID_BLKS) {
    __syncthreads();                     // LDS reuse across units
    if (unit < BB) {                     // ---- compact (verified R6/R8) ----
      const int b = unit;
      int m[4];
#pragma unroll
      for (int k = 0; k < 4; ++k) m[k] = P.mask[(4 * t + k) * BB + b] ? 1 : 0;
      int cnt = m[0] + m[1] + m[2] + m[3];
      int pre = cnt;
#pragma unroll
      for (int off = 1; off < 64; off <<= 1) {
        int y = __shfl_up(pre, off, 64);
        if (lane >= off) pre += y;
      }
      if (lane == 63) u.cp.wsum[wid] = pre;
      float sv_ = (t < UU) ? P.scale[t] : 0.f;
#pragma unroll
      for (int off = 32; off > 0; off >>= 1) sv_ += __shfl_xor(sv_, off, 64);
      if (t == 0)  u.cp.sred[0] = sv_;
      if (t == 64) u.cp.sred[1] = sv_;
      __syncthreads();
      int base = 0;
#pragma unroll
      for (int w = 0; w < 4; ++w) if (w < wid) base += u.cp.wsum[w];
      int total = u.cp.wsum[0] + u.cp.wsum[1] + u.cp.wsum[2] + u.cp.wsum[3];
      int idx = base + pre - cnt;
#pragma unroll
      for (int k = 0; k < 4; ++k)
        if (m[k]) P.vidx[b * TV + (idx++)] = 4 * t + k;
      for (int i = t; i < TV; i += 256)
        if (i >= total) P.vidx[b * TV + i] = 0;   // pad with valid row 0
      if (t == 0)
        __hip_atomic_store(&P.nvalid[b], total, __ATOMIC_RELEASE,
                           __HIP_MEMORY_SCOPE_AGENT);
      if (b == 0 && t == 0)
        __hip_atomic_store(&P.Ssum[0], u.cp.sred[0] + u.cp.sred[1],
                           __ATOMIC_RELEASE, __HIP_MEMORY_SCOPE_AGENT);
    } else {                             // ---- proj, LDS-free (R7 form) ----
      const int R0 = (unit - BB) * 8;
      const bool isq = (R0 < TQ * BB);
      const float* X = isq ? P.query : P.value;
      const float* W = isq ? P.W1 : P.W2;
      float* E       = isq ? P.Eq : P.Ek;
      const int T    = isq ? TQ : TV;
      const int Rb   = isq ? R0 : (R0 - TQ * BB);
      const int uu_  = t & 127;
      const int half = t >> 7;
      const float* x0 = X + (size_t)(Rb + half * 4) * DD;  // wave-uniform rows
      float a0 = 0.f, a1 = 0.f, a2 = 0.f, a3 = 0.f;
#pragma unroll 8
      for (int d = 0; d < DD; ++d) {
        float wv = W[d * UU + uu_];               // coalesced L2 load
        a0 = __builtin_fmaf(x0[d], wv, a0);       // x0[*] uniform -> s_load
        a1 = __builtin_fmaf(x0[DD + d], wv, a1);
        a2 = __builtin_fmaf(x0[2 * DD + d], wv, a2);
        a3 = __builtin_fmaf(x0[3 * DD + d], wv, a3);
      }
      float av[4] = {a0, a1, a2, a3};
#pragma unroll
      for (int i = 0; i < 4; ++i) {
        int rf = Rb + half * 4 + i;
        int b2 = rf & (BB - 1), tt = rf >> 2;
        E[((size_t)b2 * T + tt) * UU + uu_] =
            __builtin_amdgcn_exp2f(av[i] * C2LOG2E);  // exp(2*proj)
      }
    }
  }

  __threadfence();
  grid.sync();

  // ===== P2: scores over compact tiles (grid-stride, 16q x 64v) ===========
  int nvl[BB], vtb[BB];
#pragma unroll
  for (int b2 = 0; b2 < BB; ++b2) {
    nvl[b2] = __hip_atomic_load(&P.nvalid[b2], __ATOMIC_ACQUIRE,
                                __HIP_MEMORY_SCOPE_AGENT);
    vtb[b2] = (nvl[b2] + 63) >> 6;
  }
  const int totTiles = 16 * (vtb[0] + vtb[1] + vtb[2] + vtb[3]);
  const float S = __hip_atomic_load(&P.Ssum[0], __ATOMIC_ACQUIRE,
                                    __HIP_MEMORY_SCOPE_AGENT);

  for (int T_ = bid; T_ < totTiles; T_ += GRID_BLKS) {
    int rem = T_, b = 0;
    while (b < BB - 1 && rem >= 16 * vtb[b]) { rem -= 16 * vtb[b]; ++b; }
    const int qt = rem / vtb[b];
    const int vt = rem - qt * vtb[b];
    const int q0 = qt * 16, v0 = vt * 64;

    __syncthreads();   // previous tile's LDS reads done
    {  // stage Eq tile 16x128 (linear)
      const float4* gq = (const float4*)P.Eq + ((size_t)(b * TQ + q0)) * 32;
      u.sc.eq[t]       = gq[t];
      u.sc.eq[256 + t] = gq[256 + t];
    }
    {  // stage Ek tile 64x128, gathered via vidx, col ^ (row&7) swizzle
      const float4* gk = (const float4*)P.Ek;
#pragma unroll
      for (int k = 0; k < 8; ++k) {
        int i = k * 256 + t;
        int r = i >> 5, c = i & 31;
        int row = P.vidx[b * TV + v0 + r];
        u.sc.ek[r * 32 + (c ^ (r & 7))] = gk[((size_t)(b * TV + row)) * 32 + c];
      }
    }
    __syncthreads();

    const int qp = t >> 5;             // 0..7 -> q rows {2qp, 2qp+1}
    const int vp = t & 31;             // v cols {vp, vp+32}
    const int sx = vp & 7;
    const float4* Ar0 = u.sc.eq + (2 * qp) * 32;
    const float4* Ar1 = Ar0 + 32;
    const float4* Kr0 = u.sc.ek + vp * 32;
    const float4* Kr1 = u.sc.ek + (vp + 32) * 32;
    const float4* S4  = (const float4*)P.scale;   // uniform -> scalar loads

    float a00 = 0.f, a01 = 0.f, a10 = 0.f, a11 = 0.f;
#pragma unroll 8
    for (int uu = 0; uu < 32; ++uu) {
      float4 A0 = Ar0[uu];
      float4 A1 = Ar1[uu];
      int cs = uu ^ sx;
      float4 K0 = Kr0[cs];
      float4 K1 = Kr1[cs];
      float4 sv = S4[uu];
      QUAD(A0, K0, a00)
      QUAD(A0, K1, a01)
      QUAD(A1, K0, a10)
      QUAD(A1, K1, a11)
    }
    float* row0 = P.scores + ((size_t)(b * TQ + q0 + 2 * qp)) * TV + v0;
    row0[vp]           = __builtin_fmaf(-2.f, a00, S);
    row0[vp + 32]      = __builtin_fmaf(-2.f, a01, S);
    row0[TV + vp]      = __builtin_fmaf(-2.f, a10, S);
    row0[TV + vp + 32] = __builtin_fmaf(-2.f, a11, S);
  }

  __threadfence();
  grid.sync();

  // ===== P3: softmax + context (blocks 0..255, 4 q rows each) =============
  if (bid < BB * TQ / 4) {
    const int b  = bid >> 6;
    const int q0 = (bid & 63) * 4;
    const int nv = nvl[b];
    const int w  = wid;                 // wave w owns softmax row j = w

    __syncthreads();                    // P2 LDS reads done before cx reuse
    const float* srow = P.scores + ((size_t)(b * TQ + q0 + w)) * TV;
    float4 x[4];
#pragma unroll
    for (int k = 0; k < 4; ++k) {
      float4 xv = ((const float4*)srow)[lane + 64 * k];
      int e = 4 * (lane + 64 * k);
      xv.x = (e + 0 < nv) ? xv.x : NEG_INF;
      xv.y = (e + 1 < nv) ? xv.y : NEG_INF;
      xv.z = (e + 2 < nv) ? xv.z : NEG_INF;
      xv.w = (e + 3 < nv) ? xv.w : NEG_INF;
      x[k] = xv;
    }
    float mm = NEG_INF;
#pragma unroll
    for (int k = 0; k < 4; ++k)
      mm = fmaxf(mm, fmaxf(fmaxf(x[k].x, x[k].y), fmaxf(x[k].z, x[k].w)));
#pragma unroll
    for (int off = 32; off > 0; off >>= 1)
      mm = fmaxf(mm, __shfl_xor(mm, off, 64));

    float ss = 0.f;
#pragma unroll
    for (int k = 0; k < 4; ++k) {
      float4 p;
      p.x = __expf(x[k].x - mm);
      p.y = __expf(x[k].y - mm);
      p.z = __expf(x[k].z - mm);
      p.w = __expf(x[k].w - mm);
      ((float4*)&u.cx.p[w][0])[lane + 64 * k] = p;   // masked i -> p == 0
      ss += (p.x + p.y) + (p.z + p.w);
    }
#pragma unroll
    for (int off = 32; off > 0; off >>= 1) ss += __shfl_xor(ss, off, 64);
    if (lane == 0) u.cx.red[w] = ss;
    __syncthreads();

    // ctx: wave w takes chunks c = w, w+4, ...; 4 v per chunk; d = 2*lane
    const int nChunks = (nv + 3) >> 2;
    float2 acc[4];
#pragma unroll
    for (int j = 0; j < 4; ++j) acc[j] = make_float2(0.f, 0.f);
    const float* vb  = P.value + b * DD + 2 * lane;
    const int*   vix = P.vidx + b * TV;
    for (int c = w; c < nChunks; c += 4) {
      int4 id4 = ((const int4*)vix)[c];
      float4 p0 = ((const float4*)&u.cx.p[0][0])[c];   // uniform -> broadcast
      float4 p1 = ((const float4*)&u.cx.p[1][0])[c];
      float4 p2 = ((const float4*)&u.cx.p[2][0])[c];
      float4 p3 = ((const float4*)&u.cx.p[3][0])[c];
      float2 v0_ = *(const float2*)(vb + (size_t)id4.x * (BB * DD));
      float2 v1_ = *(const float2*)(vb + (size_t)id4.y * (BB * DD));
      float2 v2_ = *(const float2*)(vb + (size_t)id4.z * (BB * DD));
      float2 v3_ = *(const float2*)(vb + (size_t)id4.w * (BB * DD));
#define ACC(pj, j)                                                     \
      acc[j].x = __builtin_fmaf(pj.x, v0_.x, acc[j].x);                \
      acc[j].y = __builtin_fmaf(pj.x, v0_.y, acc[j].y);                \
      acc[j].x = __builtin_fmaf(pj.y, v1_.x, acc[j].x);                \
      acc[j].y = __builtin_fmaf(pj.y, v1_.y, acc[j].y);                \
      acc[j].x = __builtin_fmaf(pj.z, v2_.x, acc[j].x);                \
      acc[j].y = __builtin_fmaf(pj.z, v2_.y, acc[j].y);                \
      acc[j].x = __builtin_fmaf(pj.w, v3_.x, acc[j].x);                \
      acc[j].y = __builtin_fmaf(pj.w, v3_.y, acc[j].y);
      ACC(p0, 0) ACC(p1, 1) ACC(p2, 2) ACC(p3, 3)
#undef ACC
    }
    if (w > 0) {
#pragma unroll
      for (int j = 0; j < 4; ++j)
        *(float2*)&u.cx.part[w - 1][j][2 * lane] = acc[j];
    }
    __syncthreads();
    if (w == 0) {
#pragma unroll
      for (int j = 0; j < 4; ++j) {
        float2 tot = acc[j];
        tot.x += u.cx.part[0][j][2 * lane] + u.cx.part[1][j][2 * lane] +
                 u.cx.part[2][j][2 * lane];
        tot.y += u.cx.part[0][j][2 * lane + 1] + u.cx.part[1][j][2 * lane + 1] +
                 u.cx.part[2][j][2 * lane + 1];
        float iv = 1.f / u.cx.red[j];
        float2 o = make_float2(tot.x * iv, tot.y * iv);
        *(float2*)&P.out[((size_t)(q0 + j) * BB + b) * DD + 2 * lane] = o;
      }
    }
  }
}

// ======================= FALLBACK: verified round-8 path ====================
union SharedA {
  struct { float Wl[DD * UU]; float xs[8][DD]; } pj;
  struct { int wsum[4]; float sred[2]; } cp;
};

__global__ __launch_bounds__(256) void prep_kernel(
    const float* __restrict__ query, const float* __restrict__ value,
    const float* __restrict__ W1, const float* __restrict__ W2,
    const int* __restrict__ mask, const float* __restrict__ scale,
    float* __restrict__ Eq, float* __restrict__ Ek,
    int* __restrict__ valid_idx, int* __restrict__ nvalid,
    float* __restrict__ Ssum)
{
  __shared__ SharedA u;
  const int t = threadIdx.x, lane = t & 63, wid = t >> 6;
  const int bid = blockIdx.x;

  if (bid < BB) {
    const int b = bid;
    int m[4];
#pragma unroll
    for (int k = 0; k < 4; ++k) m[k] = mask[(4 * t + k) * BB + b] ? 1 : 0;
    int cnt = m[0] + m[1] + m[2] + m[3];
    int pre = cnt;
#pragma unroll
    for (int off = 1; off < 64; off <<= 1) {
      int y = __shfl_up(pre, off, 64);
      if (lane >= off) pre += y;
    }
    if (lane == 63) u.cp.wsum[wid] = pre;
    float sv_ = (t < UU) ? scale[t] : 0.f;
#pragma unroll
    for (int off = 32; off > 0; off >>= 1) sv_ += __shfl_xor(sv_, off, 64);
    if (t == 0)  u.cp.sred[0] = sv_;
    if (t == 64) u.cp.sred[1] = sv_;
    __syncthreads();
    int base = 0;
#pragma unroll
    for (int w = 0; w < 4; ++w) if (w < wid) base += u.cp.wsum[w];
    int total = u.cp.wsum[0] + u.cp.wsum[1] + u.cp.wsum[2] + u.cp.wsum[3];
    int idx = base + pre - cnt;
#pragma unroll
    for (int k = 0; k < 4; ++k)
      if (m[k]) valid_idx[b * TV + (idx++)] = 4 * t + k;
    for (int i = t; i < TV; i += 256)
      if (i >= total) valid_idx[b * TV + i] = 0;
    if (t == 0) nvalid[b] = total;
    if (b == 0 && t == 0) Ssum[0] = u.cp.sred[0] + u.cp.sred[1];
  } else {
    const int blk = bid - BB;
    const bool isq = blk < (TQ * BB / 8);
    const float* X = isq ? query : value;
    const float* W = isq ? W1 : W2;
    float* E       = isq ? Eq : Ek;
    const int T    = isq ? TQ : TV;
    const int R0   = (isq ? blk : blk - TQ * BB / 8) * 8;

    const float4* Wg = (const float4*)W;
    float4* Wl4 = (float4*)u.pj.Wl;
#pragma unroll
    for (int k = 0; k < 16; ++k)
      Wl4[k * 256 + t] = Wg[k * 256 + t];
    ((float4*)u.pj.xs)[t] = ((const float4*)(X + (size_t)R0 * DD))[t];
    __syncthreads();

    const int half = t >> 7;
    const int uu_ = t & 127;
    float a[4] = {0.f, 0.f, 0.f, 0.f};
#pragma unroll 4
    for (int d = 0; d < DD; ++d) {
      float wv = u.pj.Wl[d * UU + uu_];
#pragma unroll
      for (int i = 0; i < 4; ++i)
        a[i] += u.pj.xs[half * 4 + i][d] * wv;
    }
#pragma unroll
    for (int i = 0; i < 4; ++i) {
      int rf = R0 + half * 4 + i;
      int b2 = rf & (BB - 1), tt = rf >> 2;
      E[((size_t)b2 * T + tt) * UU + uu_] =
          __builtin_amdgcn_exp2f(a[i] * C2LOG2E);
    }
  }
}

__global__ __launch_bounds__(256, 4) void scores_kernel(
    const float* __restrict__ Eq, const float* __restrict__ Ek,
    const float* __restrict__ scale, const float* __restrict__ Ssum,
    const int* __restrict__ valid_idx, const int* __restrict__ nvalid,
    float* __restrict__ scores)
{
  const int b  = blockIdx.z;
  const int nv = nvalid[b];
  const int v0 = blockIdx.x * 64;
  if (v0 >= nv) return;
  const int q0 = blockIdx.y * 16;
  const int t  = threadIdx.x;

  __shared__ float4 eq_lds[16 * 32];
  __shared__ float4 ek_lds[64 * 32];
  __shared__ int    vidx[64];

  if (t < 64) vidx[t] = valid_idx[b * TV + v0 + t];
  {
    const float4* gq = (const float4*)Eq + ((size_t)(b * TQ + q0)) * 32;
    eq_lds[t]       = gq[t];
    eq_lds[256 + t] = gq[256 + t];
  }
  __syncthreads();
  {
    const float4* gk = (const float4*)Ek;
#pragma unroll
    for (int k = 0; k < 8; ++k) {
      int i = k * 256 + t;
      int r = i >> 5, c = i & 31;
      ek_lds[r * 32 + (c ^ (r & 7))] =
          gk[((size_t)(b * TV + vidx[r])) * 32 + c];
    }
  }
  __syncthreads();

  const int qp = t >> 5;
  const int vp = t & 31;
  const int sx = vp & 7;
  const float4* Ar0 = eq_lds + (2 * qp) * 32;
  const float4* Ar1 = Ar0 + 32;
  const float4* Kr0 = ek_lds + vp * 32;
  const float4* Kr1 = ek_lds + (vp + 32) * 32;
  const float4* S4  = (const float4*)scale;

  float a00 = 0.f, a01 = 0.f, a10 = 0.f, a11 = 0.f;
#pragma unroll 8
  for (int uu = 0; uu < 32; ++uu) {
    float4 A0 = Ar0[uu];
    float4 A1 = Ar1[uu];
    int cs = uu ^ sx;
    float4 K0 = Kr0[cs];
    float4 K1 = Kr1[cs];
    float4 sv = S4[uu];
    QUAD(A0, K0, a00)
    QUAD(A0, K1, a01)
    QUAD(A1, K0, a10)
    QUAD(A1, K1, a11)
  }
  const float S = Ssum[0];
  float* row0 = scores + ((size_t)(b * TQ + q0 + 2 * qp)) * TV + v0;
  row0[vp]           = __builtin_fmaf(-2.f, a00, S);
  row0[vp + 32]      = __builtin_fmaf(-2.f, a01, S);
  row0[TV + vp]      = __builtin_fmaf(-2.f, a10, S);
  row0[TV + vp + 32] = __builtin_fmaf(-2.f, a11, S);
}

__global__ __launch_bounds__(512) void softmax_ctx_kernel(
    const float* __restrict__ value, const int* __restrict__ valid_idx,
    const int* __restrict__ nvalid, const float* __restrict__ scores,
    float* __restrict__ out)
{
  const int bi = blockIdx.x;
  const int b  = bi >> 6;
  const int q0 = (bi & 63) * 4;
  const int nv = nvalid[b];
  const int t = threadIdx.x, lane = t & 63;

  __shared__ float p_lds[4][TV];
  __shared__ int   vidx[TV];
  __shared__ float redm[4][2];
  __shared__ float reds[4][2];
  __shared__ float part[3][4][DD];

  if (t < 256) ((int4*)vidx)[t] = ((const int4*)(valid_idx + b * TV))[t];

  const int j = t >> 7;
  const int c = t & 127;
  const int wslot = (t >> 6) & 1;

  const float* srow = scores + ((size_t)(b * TQ + q0 + j)) * TV;
  float4 x0 = ((const float4*)srow)[c];
  float4 x1 = ((const float4*)srow)[c + 128];
  const int e0 = 4 * c, e1 = 512 + 4 * c;
  x0.x = (e0 + 0 < nv) ? x0.x : NEG_INF;
  x0.y = (e0 + 1 < nv) ? x0.y : NEG_INF;
  x0.z = (e0 + 2 < nv) ? x0.z : NEG_INF;
  x0.w = (e0 + 3 < nv) ? x0.w : NEG_INF;
  x1.x = (e1 + 0 < nv) ? x1.x : NEG_INF;
  x1.y = (e1 + 1 < nv) ? x1.y : NEG_INF;
  x1.z = (e1 + 2 < nv) ? x1.z : NEG_INF;
  x1.w = (e1 + 3 < nv) ? x1.w : NEG_INF;

  float mm = fmaxf(fmaxf(fmaxf(x0.x, x0.y), fmaxf(x0.z, x0.w)),
                   fmaxf(fmaxf(x1.x, x1.y), fmaxf(x1.z, x1.w)));
#pragma unroll
  for (int off = 32; off > 0; off >>= 1)
    mm = fmaxf(mm, __shfl_xor(mm, off, 64));
  if (lane == 0) redm[j][wslot] = mm;
  __syncthreads();
  mm = fmaxf(redm[j][0], redm[j][1]);

  float4 p0, p1;
  p0.x = __expf(x0.x - mm); p0.y = __expf(x0.y - mm);
  p0.z = __expf(x0.z - mm); p0.w = __expf(x0.w - mm);
  p1.x = __expf(x1.x - mm); p1.y = __expf(x1.y - mm);
  p1.z = __expf(x1.z - mm); p1.w = __expf(x1.w - mm);
  ((float4*)&p_lds[j][0])[c]       = p0;
  ((float4*)&p_lds[j][0])[c + 128] = p1;

  float ss = ((p0.x + p0.y) + (p0.z + p0.w)) +
             ((p1.x + p1.y) + (p1.z + p1.w));
#pragma unroll
  for (int off = 32; off > 0; off >>= 1)
    ss += __shfl_xor(ss, off, 64);
  if (lane == 0) reds[j][wslot] = ss;
  __syncthreads();

  const int qtr = t >> 7;
  const int d = t & 127;
  const int nChunks = (nv + 3) >> 2;
  float a0 = 0.f, a1 = 0.f, a2 = 0.f, a3 = 0.f;
  const float* vbase = value + b * DD + d;
  for (int ch = qtr; ch < nChunks; ch += 4) {
    int4 id = ((const int4*)vidx)[ch];
    float4 q0v = ((const float4*)&p_lds[0][0])[ch];
    float4 q1v = ((const float4*)&p_lds[1][0])[ch];
    float4 q2v = ((const float4*)&p_lds[2][0])[ch];
    float4 q3v = ((const float4*)&p_lds[3][0])[ch];
    float v0_ = vbase[(size_t)id.x * (BB * DD)];
    float v1_ = vbase[(size_t)id.y * (BB * DD)];
    float v2_ = vbase[(size_t)id.z * (BB * DD)];
    float v3_ = vbase[(size_t)id.w * (BB * DD)];
    a0 = __builtin_fmaf(q0v.x, v0_, a0); a0 = __builtin_fmaf(q0v.y, v1_, a0);
    a0 = __builtin_fmaf(q0v.z, v2_, a0); a0 = __builtin_fmaf(q0v.w, v3_, a0);
    a1 = __builtin_fmaf(q1v.x, v0_, a1); a1 = __builtin_fmaf(q1v.y, v1_, a1);
    a1 = __builtin_fmaf(q1v.z, v2_, a1); a1 = __builtin_fmaf(q1v.w, v3_, a1);
    a2 = __builtin_fmaf(q2v.x, v0_, a2); a2 = __builtin_fmaf(q2v.y, v1_, a2);
    a2 = __builtin_fmaf(q2v.z, v2_, a2); a2 = __builtin_fmaf(q2v.w, v3_, a2);
    a3 = __builtin_fmaf(q3v.x, v0_, a3); a3 = __builtin_fmaf(q3v.y, v1_, a3);
    a3 = __builtin_fmaf(q3v.z, v2_, a3); a3 = __builtin_fmaf(q3v.w, v3_, a3);
  }
  if (qtr) {
    part[qtr - 1][0][d] = a0;
    part[qtr - 1][1][d] = a1;
    part[qtr - 1][2][d] = a2;
    part[qtr - 1][3][d] = a3;
  }
  __syncthreads();
  if (qtr == 0) {
    float tot[4] = {a0, a1, a2, a3};
#pragma unroll
    for (int jj = 0; jj < 4; ++jj) {
      float s = tot[jj] + part[0][jj][d] + part[1][jj][d] + part[2][jj][d];
      float iv = 1.f / (reds[jj][0] + reds[jj][1]);
      out[((size_t)(q0 + jj) * BB + b) * DD + d] = s * iv;
    }
  }
}

extern "C" void kernel_launch(void* const* d_in, const int* in_sizes, int n_in,
                              void* d_out, int out_size, void* d_ws, size_t ws_size,
                              hipStream_t stream) {
  Params P;
  P.query = (const float*)d_in[0];
  P.value = (const float*)d_in[1];
  P.mask  = (const int*)  d_in[2];
  P.W1    = (const float*)d_in[3];
  P.W2    = (const float*)d_in[4];
  P.scale = (const float*)d_in[5];
  P.out   = (float*)d_out;

  float* ws = (float*)d_ws;
  P.Eq     = ws;                                   // [B,TQ,U]
  P.Ek     = P.Eq + (size_t)BB * TQ * UU;          // [B,TV,U]
  P.scores = P.Ek + (size_t)BB * TV * UU;          // [B,TQ,TV]
  P.vidx   = (int*)(P.scores + (size_t)BB * TQ * TV);  // [B,TV]
  P.nvalid = P.vidx + BB * TV;                     // [B]
  P.Ssum   = (float*)(P.nvalid + BB);              // [1]

  void* args[] = { (void*)&P };
  hipError_t err = hipLaunchCooperativeKernel(
      (const void*)fused_kernel, dim3(GRID_BLKS), dim3(256), args, 0, stream);
  if (err != hipSuccess) {
    (void)hipGetLastError();   // clear error state, use fallback path
    prep_kernel<<<BB + (TQ + TV) * BB / 8, 256, 0, stream>>>(
        P.query, P.value, P.W1, P.W2, P.mask, P.scale,
        P.Eq, P.Ek, P.vidx, P.nvalid, P.Ssum);
    scores_kernel<<<dim3(TV / 64, TQ / 16, BB), 256, 0, stream>>>(
        P.Eq, P.Ek, P.scale, P.Ssum, P.vidx, P.nvalid, P.scores);
    softmax_ctx_kernel<<<BB * TQ / 4, 512, 0, stream>>>(
        P.value, P.vidx, P.nvalid, P.scores, P.out);
  }
}

// Round 10
// 55.726 us; speedup vs baseline: 6.4170x; 6.4170x over previous
//
#include <hip/hip_runtime.h>

// Bahdanau additive attention, fp32, 2 kernels.
// score[b,q,v] = S - 2*sum_u s_u / (1 + Eq[q,u]*Ek[v,u]),  E* = exp(2*proj)
// query [TQ,B,D], value [TV,B,D], mask [TV,B] (int32), W1 [D,U], W2 [D,U], scale [U]

#define TQ 256
#define TV 1024
#define BB 4
#define DD 128
#define UU 128
#define NEG_INF -1e9f
#define C2LOG2E 2.8853900817779268f   // 2*log2(e)

// 4-batched reciprocal, single accumulator: 16 VALU + 1 rcp per 4 terms
#define QUAD1(Av, Kv, sv, acc)                                     \
  { float d0 = __builtin_fmaf(Av.x, Kv.x, 1.f);                    \
    float d1 = __builtin_fmaf(Av.y, Kv.y, 1.f);                    \
    float d2 = __builtin_fmaf(Av.z, Kv.z, 1.f);                    \
    float d3 = __builtin_fmaf(Av.w, Kv.w, 1.f);                    \
    float m01 = d0 * d1, m23 = d2 * d3;                            \
    float R = __builtin_amdgcn_rcpf(m01 * m23);                    \
    float q01 = R * m23, q23 = R * m01;                            \
    acc = __builtin_fmaf(sv.x, q01 * d1, acc);                     \
    acc = __builtin_fmaf(sv.y, q01 * d0, acc);                     \
    acc = __builtin_fmaf(sv.z, q23 * d3, acc);                     \
    acc = __builtin_fmaf(sv.w, q23 * d2, acc); }

// ============ kernel 1: compact (blocks 0..3) + proj (rest) — verified R8 ===
union SharedA {
  struct { float Wl[DD * UU]; float xs[8][DD]; } pj;
  struct { int wsum[4]; float sred[2]; } cp;
};

__global__ __launch_bounds__(256) void prep_kernel(
    const float* __restrict__ query, const float* __restrict__ value,
    const float* __restrict__ W1, const float* __restrict__ W2,
    const int* __restrict__ mask, const float* __restrict__ scale,
    float* __restrict__ Eq, float* __restrict__ Ek,
    int* __restrict__ valid_idx, int* __restrict__ nvalid,
    float* __restrict__ Ssum)
{
  __shared__ SharedA u;
  const int t = threadIdx.x, lane = t & 63, wid = t >> 6;
  const int bid = blockIdx.x;

  if (bid < BB) {
    const int b = bid;
    int m[4];
#pragma unroll
    for (int k = 0; k < 4; ++k) m[k] = mask[(4 * t + k) * BB + b] ? 1 : 0;
    int cnt = m[0] + m[1] + m[2] + m[3];
    int pre = cnt;
#pragma unroll
    for (int off = 1; off < 64; off <<= 1) {
      int y = __shfl_up(pre, off, 64);
      if (lane >= off) pre += y;
    }
    if (lane == 63) u.cp.wsum[wid] = pre;
    float sv_ = (t < UU) ? scale[t] : 0.f;
#pragma unroll
    for (int off = 32; off > 0; off >>= 1) sv_ += __shfl_xor(sv_, off, 64);
    if (t == 0)  u.cp.sred[0] = sv_;
    if (t == 64) u.cp.sred[1] = sv_;
    __syncthreads();
    int base = 0;
#pragma unroll
    for (int w = 0; w < 4; ++w) if (w < wid) base += u.cp.wsum[w];
    int total = u.cp.wsum[0] + u.cp.wsum[1] + u.cp.wsum[2] + u.cp.wsum[3];
    int idx = base + pre - cnt;
#pragma unroll
    for (int k = 0; k < 4; ++k)
      if (m[k]) valid_idx[b * TV + (idx++)] = 4 * t + k;
    for (int i = t; i < TV; i += 256)
      if (i >= total) valid_idx[b * TV + i] = 0;  // pad with valid row 0
    if (t == 0) nvalid[b] = total;
    if (b == 0 && t == 0) Ssum[0] = u.cp.sred[0] + u.cp.sred[1];
  } else {
    const int blk = bid - BB;
    const bool isq = blk < (TQ * BB / 8);
    const float* X = isq ? query : value;
    const float* W = isq ? W1 : W2;
    float* E       = isq ? Eq : Ek;
    const int T    = isq ? TQ : TV;
    const int R0   = (isq ? blk : blk - TQ * BB / 8) * 8;

    const float4* Wg = (const float4*)W;
    float4* Wl4 = (float4*)u.pj.Wl;
#pragma unroll
    for (int k = 0; k < 16; ++k)
      Wl4[k * 256 + t] = Wg[k * 256 + t];
    ((float4*)u.pj.xs)[t] = ((const float4*)(X + (size_t)R0 * DD))[t];
    __syncthreads();

    const int half = t >> 7;
    const int uu_ = t & 127;
    float a[4] = {0.f, 0.f, 0.f, 0.f};
#pragma unroll 4
    for (int d = 0; d < DD; ++d) {
      float wv = u.pj.Wl[d * UU + uu_];
#pragma unroll
      for (int i = 0; i < 4; ++i)
        a[i] += u.pj.xs[half * 4 + i][d] * wv;
    }
#pragma unroll
    for (int i = 0; i < 4; ++i) {
      int rf = R0 + half * 4 + i;
      int b2 = rf & (BB - 1), tt = rf >> 2;
      E[((size_t)b2 * T + tt) * UU + uu_] =
          __builtin_amdgcn_exp2f(a[i] * C2LOG2E);   // exp(2*proj)
    }
  }
}

// ============ kernel 2: flash-style scores + softmax + context ==============
// Block = (b, 4 q-rows). 256 blocks x 512 threads. Loops 128-v compact tiles.
__global__ __launch_bounds__(512, 1) void attn_kernel(
    const float* __restrict__ value,     // [TV,B,D]
    const float* __restrict__ Eq,        // [B,TQ,U]
    const float* __restrict__ Ek,        // [B,TV,U]
    const float* __restrict__ scale,     // [U]
    const float* __restrict__ Ssum,      // [1]
    const int*   __restrict__ valid_idx, // [B,TV]
    const int*   __restrict__ nvalid,    // [B]
    float* __restrict__ out)             // [TQ,B,D]
{
  const int bid = blockIdx.x;
  const int b   = bid >> 6;
  const int q0  = (bid & 63) * 4;
  const int t   = threadIdx.x;
  const int lane = t & 63;

  __shared__ float4 kv_lds[128 * 32];      // 64 KB: Ek tile, then V tile
  __shared__ float  s_lds[4][TV];          // 16 KB: scores -> p
  __shared__ float4 eq_lds[4 * 32];        // 2 KB
  __shared__ int    vidx[TV];              // 4 KB
  __shared__ float  redm[4][2], redsum[4][2], inv_s[4];
  __shared__ float  part[4][64][2];        // 2 KB

  const int nv  = nvalid[b];
  const int nvt = (nv + 127) >> 7;         // 128-v tiles
  const float S = Ssum[0];

  if (t < 256) ((int4*)vidx)[t] = ((const int4*)(valid_idx + b * TV))[t];
  if (t < 128) eq_lds[t] = ((const float4*)Eq)[((size_t)(b * TQ + q0)) * 32 + t];
  __syncthreads();

  // ---- scores: thread = (q = t>>7, vl = t&127), one score per tile ----
  const int q  = t >> 7;
  const int vl = t & 127;
  const int sx = vl & 7;
  const float4* S4 = (const float4*)scale;     // wave-uniform -> s_load

  for (int tix = 0; tix < nvt; ++tix) {
    if (tix) __syncthreads();                  // prior tile's reads done
    {  // stage Ek tile (128 compact rows), col ^ (row&7) swizzle
      const float4* gk = (const float4*)Ek;
#pragma unroll
      for (int k = 0; k < 8; ++k) {
        int i = k * 512 + t;
        int r = i >> 5, c = i & 31;
        kv_lds[r * 32 + (c ^ (r & 7))] =
            gk[((size_t)(b * TV + vidx[tix * 128 + r])) * 32 + c];
      }
    }
    __syncthreads();

    const float4* Ar = eq_lds + q * 32;        // wave-uniform row -> broadcast
    const float4* Kr = kv_lds + vl * 32;
    float acc = 0.f;
#pragma unroll 8
    for (int uu = 0; uu < 32; ++uu) {
      float4 A0 = Ar[uu];
      float4 K0 = Kr[uu ^ sx];
      float4 sv = S4[uu];
      QUAD1(A0, K0, sv, acc)
    }
    s_lds[q][tix * 128 + vl] = __builtin_fmaf(-2.f, acc, S);
  }
  __syncthreads();

  // ---- softmax row q over nv slots; 128 threads (2 waves) per row ----
  const int wslot = (t >> 6) & 1;
  float mm = NEG_INF;
#pragma unroll
  for (int k = 0; k < 8; ++k) {
    int gv = vl + 128 * k;
    float x = (gv < nv) ? s_lds[q][gv] : NEG_INF;
    mm = fmaxf(mm, x);
  }
#pragma unroll
  for (int off = 32; off > 0; off >>= 1)
    mm = fmaxf(mm, __shfl_xor(mm, off, 64));
  if (lane == 0) redm[q][wslot] = mm;
  __syncthreads();
  mm = fmaxf(redm[q][0], redm[q][1]);

  float ssum = 0.f;
#pragma unroll
  for (int k = 0; k < 8; ++k) {
    int gv = vl + 128 * k;
    float x = (gv < nv) ? s_lds[q][gv] : NEG_INF;
    float p = __expf(x - mm);                  // exp(-1e9 - m) == 0
    s_lds[q][gv] = p;
    ssum += p;
  }
#pragma unroll
  for (int off = 32; off > 0; off >>= 1)
    ssum += __shfl_xor(ssum, off, 64);
  if (lane == 0) redsum[q][wslot] = ssum;
  __syncthreads();
  if (t < 4) inv_s[t] = 1.f / (redsum[t][0] + redsum[t][1]);

  // ---- context: thread = (q, vh = (t>>6)&1, dp = t&63); d = 2*dp ----
  const int vh = (t >> 6) & 1;
  const int dp = t & 63;
  float ax = 0.f, ay = 0.f;

  for (int tix = 0; tix < nvt; ++tix) {
    __syncthreads();                           // prior V-tile reads / p writes done
    {  // stage V tile (128 compact rows x 128 floats), linear layout
      const float4* gv4 = (const float4*)value;
#pragma unroll
      for (int k = 0; k < 8; ++k) {
        int i = k * 512 + t;
        int r = i >> 5, c = i & 31;
        kv_lds[r * 32 + c] =
            gv4[((size_t)vidx[tix * 128 + r] * BB + b) * 32 + c];
      }
    }
    __syncthreads();

    const float* Vl = (const float*)kv_lds;
    const int lim = min(128, nv - tix * 128);
    const float* prow = &s_lds[q][tix * 128];
    for (int v = vh; v < lim; v += 2) {
      float p = prow[v];                       // same addr across wave -> bcast
      float2 vv = *(const float2*)(Vl + v * 128 + 2 * dp);
      ax = __builtin_fmaf(p, vv.x, ax);
      ay = __builtin_fmaf(p, vv.y, ay);
    }
  }

  if (vh) { part[q][dp][0] = ax; part[q][dp][1] = ay; }
  __syncthreads();
  if (!vh) {
    float iv = inv_s[q];
    float2 o = make_float2((ax + part[q][dp][0]) * iv,
                           (ay + part[q][dp][1]) * iv);
    *(float2*)&out[((size_t)(q0 + q) * BB + b) * DD + 2 * dp] = o;
  }
}

extern "C" void kernel_launch(void* const* d_in, const int* in_sizes, int n_in,
                              void* d_out, int out_size, void* d_ws, size_t ws_size,
                              hipStream_t stream) {
  const float* query = (const float*)d_in[0];  // [TQ,B,D]
  const float* value = (const float*)d_in[1];  // [TV,B,D]
  const int*   mask  = (const int*)  d_in[2];  // [TV,B]
  const float* W1    = (const float*)d_in[3];  // [D,U]
  const float* W2    = (const float*)d_in[4];  // [D,U]
  const float* scale = (const float*)d_in[5];  // [U]
  float* out = (float*)d_out;

  float* Eq      = (float*)d_ws;                    // [B,TQ,U]
  float* Ek      = Eq + (size_t)BB * TQ * UU;       // [B,TV,U]
  int*   vidx    = (int*)(Ek + (size_t)BB * TV * UU);  // [B,TV]
  int*   nvalid  = vidx + BB * TV;                  // [B]
  float* Ssum    = (float*)(nvalid + BB);           // [1]

  prep_kernel<<<BB + (TQ + TV) * BB / 8, 256, 0, stream>>>(
      query, value, W1, W2, mask, scale, Eq, Ek, vidx, nvalid, Ssum);
  attn_kernel<<<BB * TQ / 4, 512, 0, stream>>>(
      value, Eq, Ek, scale, Ssum, vidx, nvalid, out);
}

// Round 11
// 51.034 us; speedup vs baseline: 7.0070x; 1.0919x over previous
//
#include <hip/hip_runtime.h>

// Bahdanau additive attention, fp32, 2 kernels.
// score[b,q,v] = S - 2*sum_u s_u / (1 + Eq[q,u]*Ek[v,u]),  E* = exp(2*proj)
// query [TQ,B,D], value [TV,B,D], mask [TV,B] (int32), W1 [D,U], W2 [D,U], scale [U]

#define TQ 256
#define TV 1024
#define BB 4
#define DD 128
#define UU 128
#define NEG_INF -1e9f
#define C2LOG2E 2.8853900817779268f   // 2*log2(e)

// 4-batched reciprocal: 17 VALU + 1 rcp per 4 score terms
#define QUAD1(Av, Kv, sv, acc)                                     \
  { float d0 = __builtin_fmaf(Av.x, Kv.x, 1.f);                    \
    float d1 = __builtin_fmaf(Av.y, Kv.y, 1.f);                    \
    float d2 = __builtin_fmaf(Av.z, Kv.z, 1.f);                    \
    float d3 = __builtin_fmaf(Av.w, Kv.w, 1.f);                    \
    float m01 = d0 * d1, m23 = d2 * d3;                            \
    float R = __builtin_amdgcn_rcpf(m01 * m23);                    \
    float q01 = R * m23, q23 = R * m01;                            \
    acc = __builtin_fmaf(sv.x, q01 * d1, acc);                     \
    acc = __builtin_fmaf(sv.y, q01 * d0, acc);                     \
    acc = __builtin_fmaf(sv.z, q23 * d3, acc);                     \
    acc = __builtin_fmaf(sv.w, q23 * d2, acc); }

// ============ kernel 1: compact (blocks 0..3) + LDS-free proj (rest) =======
// (verified in R9's fused kernel; standalone here)
__global__ __launch_bounds__(256) void prep_kernel(
    const float* __restrict__ query, const float* __restrict__ value,
    const float* __restrict__ W1, const float* __restrict__ W2,
    const int* __restrict__ mask, const float* __restrict__ scale,
    float* __restrict__ Eq, float* __restrict__ Ek,
    int* __restrict__ valid_idx, int* __restrict__ nvalid,
    float* __restrict__ Ssum)
{
  __shared__ int   wsum[4];
  __shared__ float sred[2];
  const int t = threadIdx.x, lane = t & 63, wid = t >> 6;
  const int bid = blockIdx.x;

  if (bid < BB) {
    const int b = bid;
    int m[4];
#pragma unroll
    for (int k = 0; k < 4; ++k) m[k] = mask[(4 * t + k) * BB + b] ? 1 : 0;
    int cnt = m[0] + m[1] + m[2] + m[3];
    int pre = cnt;
#pragma unroll
    for (int off = 1; off < 64; off <<= 1) {
      int y = __shfl_up(pre, off, 64);
      if (lane >= off) pre += y;
    }
    if (lane == 63) wsum[wid] = pre;
    float sv_ = (t < UU) ? scale[t] : 0.f;
#pragma unroll
    for (int off = 32; off > 0; off >>= 1) sv_ += __shfl_xor(sv_, off, 64);
    if (t == 0)  sred[0] = sv_;
    if (t == 64) sred[1] = sv_;
    __syncthreads();
    int base = 0;
#pragma unroll
    for (int w = 0; w < 4; ++w) if (w < wid) base += wsum[w];
    int total = wsum[0] + wsum[1] + wsum[2] + wsum[3];
    int idx = base + pre - cnt;
#pragma unroll
    for (int k = 0; k < 4; ++k)
      if (m[k]) valid_idx[b * TV + (idx++)] = 4 * t + k;
    for (int i = t; i < TV; i += 256)
      if (i >= total) valid_idx[b * TV + i] = 0;  // pad with valid row 0
    if (t == 0) nvalid[b] = total;
    if (b == 0 && t == 0) Ssum[0] = sred[0] + sred[1];
  } else {
    const int R0 = (bid - BB) * 8;
    const bool isq = (R0 < TQ * BB);
    const float* X = isq ? query : value;
    const float* W = isq ? W1 : W2;
    float* E       = isq ? Eq : Ek;
    const int T    = isq ? TQ : TV;
    const int Rb   = isq ? R0 : (R0 - TQ * BB);
    const int uu_  = t & 127;
    const int half = t >> 7;
    const float* x0 = X + (size_t)(Rb + half * 4) * DD;  // wave-uniform rows
    float a0 = 0.f, a1 = 0.f, a2 = 0.f, a3 = 0.f;
#pragma unroll 8
    for (int d = 0; d < DD; ++d) {
      float wv = W[d * UU + uu_];               // coalesced L2 load
      a0 = __builtin_fmaf(x0[d], wv, a0);       // uniform x -> s_load
      a1 = __builtin_fmaf(x0[DD + d], wv, a1);
      a2 = __builtin_fmaf(x0[2 * DD + d], wv, a2);
      a3 = __builtin_fmaf(x0[3 * DD + d], wv, a3);
    }
    float av[4] = {a0, a1, a2, a3};
#pragma unroll
    for (int i = 0; i < 4; ++i) {
      int rf = Rb + half * 4 + i;
      int b2 = rf & (BB - 1), tt = rf >> 2;
      E[((size_t)b2 * T + tt) * UU + uu_] =
          __builtin_amdgcn_exp2f(av[i] * C2LOG2E);  // exp(2*proj)
    }
  }
}

// ============ kernel 2: flash attn, 2 q-rows/block, 512 blocks =============
__global__ __launch_bounds__(512, 4) void attn_kernel(
    const float* __restrict__ value,     // [TV,B,D]
    const float* __restrict__ Eq,        // [B,TQ,U]
    const float* __restrict__ Ek,        // [B,TV,U]
    const float* __restrict__ scale,     // [U]
    const float* __restrict__ Ssum,      // [1]
    const int*   __restrict__ valid_idx, // [B,TV]
    const int*   __restrict__ nvalid,    // [B]
    float* __restrict__ out)             // [TQ,B,D]
{
  const int bid = blockIdx.x;
  const int b   = bid >> 7;                 // 128 q-pairs per batch
  const int q0  = (bid & 127) * 2;
  const int t   = threadIdx.x;
  const int lane = t & 63;

  __shared__ float4 kv[128 * 32];           // 64 KB: Ek tile (swz), then V tile
  __shared__ float  s_lds[2][TV];           // 8 KB: scores -> p
  __shared__ float4 eq_lds[2 * 32];         // 1 KB, col-swizzled c^(c>>3)
  __shared__ float4 sc_lds[32];             // 512 B, col-swizzled
  __shared__ float  redm[2][4], reds[2][4], inv_s[2];
  __shared__ float  part[3][2][DD];         // 3 KB
  // total ~76.6 KB -> 2 blocks/CU

  const int nv  = nvalid[b];
  const int nvt = (nv + 127) >> 7;          // 128-v tiles
  const float S = Ssum[0];

  if (t < 64) {                             // eq: 2 rows, col-swizzled
    int row = t >> 5, c = t & 31;
    eq_lds[row * 32 + (c ^ (c >> 3))] =
        ((const float4*)Eq)[((size_t)(b * TQ + q0 + row)) * 32 + c];
  } else if (t < 96) {                      // scale, col-swizzled
    int c = t & 31;
    sc_lds[c ^ (c >> 3)] = ((const float4*)scale)[c];
  }

  // ---- score phase: thread = (vl = t>>2, uq = t&3); both q in registers ----
  const int vl = t >> 2;
  const int uq = t & 3;
  const int sx = vl & 7;

  for (int tix = 0; tix < nvt; ++tix) {
    int rows[8];                            // issue gather rows BEFORE barrier
    const int rb = b * TV + tix * 128 + (t >> 5);
#pragma unroll
    for (int k = 0; k < 8; ++k) rows[k] = valid_idx[rb + 16 * k];
    __syncthreads();                        // eq/sc ready (tix 0) / prior reads
    {                                       // stage Ek tile, col ^ (row&7)
      const float4* gk = (const float4*)Ek;
#pragma unroll
      for (int k = 0; k < 8; ++k) {
        int i = k * 512 + t;
        int r = i >> 5, c = i & 31;
        kv[r * 32 + (c ^ (r & 7))] = gk[((size_t)(b * TV + rows[k])) * 32 + c];
      }
    }
    __syncthreads();

    float acc0 = 0.f, acc1 = 0.f;
    const float4* Kr = kv + vl * 32;
#pragma unroll
    for (int j = 0; j < 8; ++j) {
      int uu = uq * 8 + j;                  // this thread's u-quarter
      float4 K  = Kr[uu ^ sx];
      int es = uu ^ uq;                     // = uu ^ (uu>>3) swizzled col
      float4 A0 = eq_lds[es];
      float4 A1 = eq_lds[32 + es];
      float4 sv = sc_lds[es];
      QUAD1(A0, K, sv, acc0)
      QUAD1(A1, K, sv, acc1)
    }
    acc0 += __shfl_xor(acc0, 1, 64); acc0 += __shfl_xor(acc0, 2, 64);
    acc1 += __shfl_xor(acc1, 1, 64); acc1 += __shfl_xor(acc1, 2, 64);
    if (uq == 0) {
      s_lds[0][tix * 128 + vl] = __builtin_fmaf(-2.f, acc0, S);
      s_lds[1][tix * 128 + vl] = __builtin_fmaf(-2.f, acc1, S);
    }
  }
  __syncthreads();

  // ---- softmax: row sq = t>>8, 4 waves/row, 4 elems/thread ----
  const int sq = t >> 8;
  const int si = t & 255;
  const int ws = (t >> 6) & 3;
  float xv[4];
  float mm = NEG_INF;
#pragma unroll
  for (int k = 0; k < 4; ++k) {
    int gv = si + 256 * k;
    xv[k] = (gv < nv) ? s_lds[sq][gv] : NEG_INF;
    mm = fmaxf(mm, xv[k]);
  }
#pragma unroll
  for (int off = 32; off > 0; off >>= 1)
    mm = fmaxf(mm, __shfl_xor(mm, off, 64));
  if (lane == 0) redm[sq][ws] = mm;
  __syncthreads();
  mm = fmaxf(fmaxf(redm[sq][0], redm[sq][1]), fmaxf(redm[sq][2], redm[sq][3]));

  float ssum = 0.f;
#pragma unroll
  for (int k = 0; k < 4; ++k) {
    float p = __expf(xv[k] - mm);           // masked/pad -> exp(-1e9-m) == 0
    s_lds[sq][si + 256 * k] = p;
    ssum += p;
  }
#pragma unroll
  for (int off = 32; off > 0; off >>= 1)
    ssum += __shfl_xor(ssum, off, 64);
  if (lane == 0) reds[sq][ws] = ssum;
  __syncthreads();
  if (t < 2)
    inv_s[t] = 1.f / (reds[t][0] + reds[t][1] + reds[t][2] + reds[t][3]);

  // ---- context: thread = (vq = t>>7, dp = t&127), both q accumulated ----
  const int vq = t >> 7;
  const int dp = t & 127;
  float a0 = 0.f, a1 = 0.f;

  for (int tix = 0; tix < nvt; ++tix) {
    int rows[8];
    const int rb = b * TV + tix * 128 + (t >> 5);
#pragma unroll
    for (int k = 0; k < 8; ++k) rows[k] = valid_idx[rb + 16 * k];
    __syncthreads();                        // p/inv ready; prior kv reads done
    {                                       // stage V tile, linear
      const float4* gv4 = (const float4*)value;
#pragma unroll
      for (int k = 0; k < 8; ++k) {
        int i = k * 512 + t;
        int r = i >> 5, c = i & 31;
        kv[r * 32 + c] = gv4[((size_t)rows[k] * BB + b) * 32 + c];
      }
    }
    __syncthreads();

    const float* Vf = (const float*)kv;
    const float4* p40 = (const float4*)&s_lds[0][tix * 128 + vq * 32];
    const float4* p41 = (const float4*)&s_lds[1][tix * 128 + vq * 32];
#pragma unroll
    for (int c8 = 0; c8 < 8; ++c8) {
      float4 p0 = p40[c8];                  // wave-uniform -> broadcast
      float4 p1 = p41[c8];
      const float* Vr = Vf + (vq * 32 + c8 * 4) * 128 + dp;
      float v0 = Vr[0], v1 = Vr[128], v2 = Vr[256], v3 = Vr[384];
      a0 = __builtin_fmaf(p0.x, v0, a0); a1 = __builtin_fmaf(p1.x, v0, a1);
      a0 = __builtin_fmaf(p0.y, v1, a0); a1 = __builtin_fmaf(p1.y, v1, a1);
      a0 = __builtin_fmaf(p0.z, v2, a0); a1 = __builtin_fmaf(p1.z, v2, a1);
      a0 = __builtin_fmaf(p0.w, v3, a0); a1 = __builtin_fmaf(p1.w, v3, a1);
    }
  }

  if (vq) { part[vq - 1][0][dp] = a0; part[vq - 1][1][dp] = a1; }
  __syncthreads();
  if (vq == 0) {
    float o0 = a0 + part[0][0][dp] + part[1][0][dp] + part[2][0][dp];
    float o1 = a1 + part[0][1][dp] + part[1][1][dp] + part[2][1][dp];
    out[((size_t)q0 * BB + b) * DD + dp]       = o0 * inv_s[0];
    out[((size_t)(q0 + 1) * BB + b) * DD + dp] = o1 * inv_s[1];
  }
}

extern "C" void kernel_launch(void* const* d_in, const int* in_sizes, int n_in,
                              void* d_out, int out_size, void* d_ws, size_t ws_size,
                              hipStream_t stream) {
  const float* query = (const float*)d_in[0];  // [TQ,B,D]
  const float* value = (const float*)d_in[1];  // [TV,B,D]
  const int*   mask  = (const int*)  d_in[2];  // [TV,B]
  const float* W1    = (const float*)d_in[3];  // [D,U]
  const float* W2    = (const float*)d_in[4];  // [D,U]
  const float* scale = (const float*)d_in[5];  // [U]
  float* out = (float*)d_out;

  float* Eq      = (float*)d_ws;                    // [B,TQ,U]
  float* Ek      = Eq + (size_t)BB * TQ * UU;       // [B,TV,U]
  int*   vidx    = (int*)(Ek + (size_t)BB * TV * UU);  // [B,TV]
  int*   nvalid  = vidx + BB * TV;                  // [B]
  float* Ssum    = (float*)(nvalid + BB);           // [1]

  prep_kernel<<<BB + (TQ + TV) * BB / 8, 256, 0, stream>>>(
      query, value, W1, W2, mask, scale, Eq, Ek, vidx, nvalid, Ssum);
  attn_kernel<<<BB * TQ / 2, 512, 0, stream>>>(
      value, Eq, Ek, scale, Ssum, vidx, nvalid, out);
}